// Round 2
// baseline (485.746 us; speedup 1.0000x reference)
//
#include <hip/hip_runtime.h>
#include <hip/hip_bf16.h>

#define T_LEN 2048
#define E_LEN 2048
#define B_SZ  8
#define BM 128
#define BN 128
#define BK2 64          // k-tile (two 32-k MFMA sub-steps per tile)
#define WREV_LEN 4104   // 2*T + 8, even -> each shifted copy stays 16B aligned

typedef short short8 __attribute__((ext_vector_type(8)));
typedef float floatx4 __attribute__((ext_vector_type(4)));

// ---------------------------------------------------------------------------
// Prepass: 8 shift-staggered bf16 copies of the reversed, zero-padded weight.
//   wrev[j] = (j < T) ? w[T-1-j] : 0 ;  wrevs[p][q] = wrev[q + p]
// => wrev[C..C+7] is one 16B-aligned load from copy p=C&7 at (C-p).
// ---------------------------------------------------------------------------
__global__ __launch_bounds__(256) void build_wrevs(
    const float* __restrict__ w, __hip_bfloat16* __restrict__ wrevs)
{
    int total = 8 * WREV_LEN;
    for (int i = threadIdx.x + blockIdx.x * blockDim.x; i < total;
         i += blockDim.x * gridDim.x) {
        int p = i / WREV_LEN, q = i - p * WREV_LEN;
        int j = q + p;
        float v = (j < T_LEN) ? w[T_LEN - 1 - j] : 0.0f;
        wrevs[i] = __float2bfloat16(v);
    }
}

// ---------------------------------------------------------------------------
// Fused GEMM: D[e,s] = sum_t x[b][t][e] * w[s-t]   (== out[b][s][e])
// The t<->e transpose is folded into LDS staging:
//   - global: thread loads float4 pairs (rows t, t+1; lanes->e, coalesced f32)
//   - pack:   u32 = (bf16(x[t][e]), bf16(x[t+1][e]))  [low = even t]
//   - LDS:    W[buf][e 0..127][t-pair 0..31], row stride 33 u32
//             writes: 4-way bank (1.58x, cheap); frag reads: <=2-way (free)
// A fragment (8 consecutive t for lane's e-row) = 4 adjacent u32 of one row.
// T14 split: global loads for tile kt+1 issued BEFORE tile kt's MFMAs
// (bfrag loads first so their vmcnt waits leave the prefetch in flight);
// pack+ds_write after the post-compute barrier.
// B: fragments straight from wrevs (64 KB, L2-hot, no LDS).
// Causal: ktiles = (s0+BN)/64.
// XCD swizzle: lid = (bid%8)*256 + bid/8 -> each XCD gets 16 whole A-panels
// (all 16 nb-blocks of a panel on one XCD => panel fetched ~once per XCD).
// Heavy-first within panel: nb = 15 - (lid&15).
// grid: 2048, block 256 (4 waves, 64x64 quadrant each, 4x4 MFMA)
// ---------------------------------------------------------------------------
__global__ __launch_bounds__(256, 3) void toeplitz_gemm_fused(
    const float* __restrict__ x,
    const __hip_bfloat16* __restrict__ wrevs,
    const float* __restrict__ bias,
    float* __restrict__ out)
{
    const int lid = ((int)blockIdx.x & 7) * 256 + ((int)blockIdx.x >> 3);
    const int nb = 15 - (lid & 15);          // heavy tiles first within panel
    const int panel = lid >> 4;              // 0..127
    const int mb = panel & 15, b = panel >> 4;
    const int e0 = mb * BM, s0 = nb * BN;
    const int tid = threadIdx.x;
    const int wave = tid >> 6, lane = tid & 63;
    const int wm = (wave & 1) * 64;          // wave m (e) offset
    const int wn = (wave >> 1) * 64;         // wave n (s) offset
    const int ln15 = lane & 15, quad = lane >> 4;

    __shared__ unsigned int W[2][BM][33];    // 33792 B double buffer

    floatx4 acc[4][4];
    #pragma unroll
    for (int i = 0; i < 4; ++i)
        #pragma unroll
        for (int j = 0; j < 4; ++j)
            acc[i][j] = (floatx4){0.f, 0.f, 0.f, 0.f};

    const int ktiles = (s0 + BN) / BK2;      // causal bound (>= 2)
    const float* xb = x + (size_t)b * T_LEN * E_LEN;
    const short* wr = reinterpret_cast<const short*>(wrevs);

    // staging thread map: ec = e-quad (lanes->e, coalesced), tr = t-pair row
    const int ec = tid & 31;                 // e = e0 + 4*ec .. +3
    const int tr = wave * 2 + (lane >> 5);   // 0..7 (t-pair within pass)

    float4 La[4], Lb[4];                     // rows t (even), t+1 (odd)

    auto LOADX = [&](int kt) {
        const int t0 = kt * BK2;
        #pragma unroll
        for (int p2 = 0; p2 < 4; ++p2) {
            const int tp = p2 * 8 + tr;      // t-pair 0..31
            const float* g = xb + (size_t)(t0 + 2 * tp) * E_LEN + e0 + 4 * ec;
            La[p2] = *reinterpret_cast<const float4*>(g);
            Lb[p2] = *reinterpret_cast<const float4*>(g + E_LEN);
        }
    };
    auto PACKWRITE = [&](int buf) {
        #pragma unroll
        for (int p2 = 0; p2 < 4; ++p2) {
            const int tp = p2 * 8 + tr;
            const float av[4] = {La[p2].x, La[p2].y, La[p2].z, La[p2].w};
            const float bv[4] = {Lb[p2].x, Lb[p2].y, Lb[p2].z, Lb[p2].w};
            #pragma unroll
            for (int j = 0; j < 4; ++j) {
                __hip_bfloat16 ha = __float2bfloat16(av[j]);
                __hip_bfloat16 hb = __float2bfloat16(bv[j]);
                unsigned int w =
                    (unsigned int)*reinterpret_cast<unsigned short*>(&ha) |
                    ((unsigned int)*reinterpret_cast<unsigned short*>(&hb) << 16);
                W[buf][4 * ec + j][tp] = w;
            }
        }
    };

    // prologue: tile 0 staged
    LOADX(0);
    PACKWRITE(0);
    __syncthreads();
    int cur = 0;

    for (int kt = 0; kt < ktiles; ++kt) {
        const int t0 = kt * BK2;

        // B fragments FIRST so their vmcnt waits don't drain the prefetch
        short8 bfrag[2][4];
        #pragma unroll
        for (int kk = 0; kk < 2; ++kk)
            #pragma unroll
            for (int ni = 0; ni < 4; ++ni) {
                int s = s0 + wn + ni * 16 + ln15;
                int C = (T_LEN - 1) - s + t0 + kk * 32 + quad * 8;
                int p = C & 7;
                bfrag[kk][ni] = *reinterpret_cast<const short8*>(
                    wr + (size_t)p * WREV_LEN + (C - p));
            }

        // issue next tile's global loads early (latency hides under MFMAs)
        if (kt + 1 < ktiles) LOADX(kt + 1);

        #pragma unroll
        for (int kk = 0; kk < 2; ++kk) {
            short8 afrag[4];
            #pragma unroll
            for (int mi = 0; mi < 4; ++mi) {
                const int r = wm + mi * 16 + ln15;
                const unsigned int* Wr = &W[cur][r][kk * 16 + quad * 4];
                union { unsigned int u[4]; short8 s8; } t;
                t.u[0] = Wr[0]; t.u[1] = Wr[1];
                t.u[2] = Wr[2]; t.u[3] = Wr[3];
                afrag[mi] = t.s8;
            }
            #pragma unroll
            for (int mi = 0; mi < 4; ++mi)
                #pragma unroll
                for (int ni = 0; ni < 4; ++ni)
                    acc[mi][ni] = __builtin_amdgcn_mfma_f32_16x16x32_bf16(
                        afrag[mi], bfrag[kk][ni], acc[mi][ni], 0, 0, 0);
        }

        if (kt + 1 < ktiles) {
            __syncthreads();                 // readers of W[cur^1] done (kt-1)
            PACKWRITE(cur ^ 1);              // vmcnt waits on LOADX here
            __syncthreads();                 // writes visible for next iter
            cur ^= 1;
        }
    }

    // epilogue: out[b][s][e] = acc + bias[s]
    // C/D layout: col(=s) = lane&15, row(=e) = quad*4 + reg
    #pragma unroll
    for (int ni = 0; ni < 4; ++ni) {
        int s = s0 + wn + ni * 16 + ln15;
        float bv = bias[s];
        #pragma unroll
        for (int mi = 0; mi < 4; ++mi) {
            int e = e0 + wm + mi * 16 + quad * 4;
            float* dst = out + ((size_t)b * T_LEN + s) * E_LEN + e;
            floatx4 v = acc[mi][ni];
            v.x += bv; v.y += bv; v.z += bv; v.w += bv;
            *reinterpret_cast<floatx4*>(dst) = v;
        }
    }
}

// ---------------------------------------------------------------------------
extern "C" void kernel_launch(void* const* d_in, const int* in_sizes, int n_in,
                              void* d_out, int out_size, void* d_ws, size_t ws_size,
                              hipStream_t stream)
{
    const float* x    = (const float*)d_in[0];
    const float* w    = (const float*)d_in[1];
    const float* bias = (const float*)d_in[2];
    float* out = (float*)d_out;

    // workspace: [wrevs bf16: 8*WREV_LEN]
    __hip_bfloat16* wrevs = (__hip_bfloat16*)d_ws;

    build_wrevs<<<dim3(64), 256, 0, stream>>>(w, wrevs);
    toeplitz_gemm_fused<<<dim3(2048), 256, 0, stream>>>(x, wrevs, bias, out);
}

// Round 3
// 346.450 us; speedup vs baseline: 1.4021x; 1.4021x over previous
//
#include <hip/hip_runtime.h>
#include <hip/hip_bf16.h>

#define T_LEN 2048
#define E_LEN 2048
#define B_SZ  8
#define BM 256
#define BN 256
#define BK2 64          // k-tile (two 32-k MFMA sub-steps per phase)
#define WREV_LEN 4104   // 2*T + 8, even -> each shifted copy stays 16B aligned
#define CL 2312         // per-copy bf16 length of LDS B window (1156 words % 8 == 4)
#define ABUF_B 32768    // bytes per A buffer (256*64*2)
#define BOFF (3 * ABUF_B)

typedef short short8 __attribute__((ext_vector_type(8)));
typedef float floatx4 __attribute__((ext_vector_type(4)));

typedef const __attribute__((address_space(1))) void* gas_ptr;
typedef __attribute__((address_space(3))) void* lds_ptr;

// ---------------------------------------------------------------------------
// Prepass 1: xT[b][e][t] = bf16(x[b][t][e])   (proven ~BW-floor in R1)
// ---------------------------------------------------------------------------
__global__ __launch_bounds__(256) void transpose_cast(
    const float* __restrict__ x, __hip_bfloat16* __restrict__ xT)
{
    const int t0 = blockIdx.x * 64, e0 = blockIdx.y * 64, b = blockIdx.z;
    __shared__ unsigned int W[64][33];       // [e][t-pair], 8448 B
    const int tid = threadIdx.x;
    const int wave = tid >> 6, lane = tid & 63;

    const float* xb = x + (size_t)b * T_LEN * E_LEN;
    const int c = tid & 15;                  // e-quad index (e = 4c..4c+3)
    const int q = tid >> 4;                  // t-pair base (0..15)

    #pragma unroll
    for (int i = 0; i < 2; ++i) {
        const int tp = q + 16 * i;           // t-pair 0..31
        const float4 a4 = *reinterpret_cast<const float4*>(
            xb + (size_t)(t0 + 2 * tp) * E_LEN + e0 + 4 * c);
        const float4 b4 = *reinterpret_cast<const float4*>(
            xb + (size_t)(t0 + 2 * tp + 1) * E_LEN + e0 + 4 * c);
        const float av[4] = {a4.x, a4.y, a4.z, a4.w};
        const float bv[4] = {b4.x, b4.y, b4.z, b4.w};
        #pragma unroll
        for (int j = 0; j < 4; ++j) {
            __hip_bfloat16 ha = __float2bfloat16(av[j]);
            __hip_bfloat16 hb = __float2bfloat16(bv[j]);
            unsigned int w =
                (unsigned int)*reinterpret_cast<unsigned short*>(&ha) |
                ((unsigned int)*reinterpret_cast<unsigned short*>(&hb) << 16);
            W[4 * c + j][tp] = w;
        }
    }
    __syncthreads();

    __hip_bfloat16* xTb = xT + (size_t)b * E_LEN * T_LEN;
    const int er = lane >> 3;                // 0..7
    const int pc = (lane & 7) * 4;           // uint col 0,4,..,28
    #pragma unroll
    for (int i = 0; i < 2; ++i) {
        const int e = wave * 8 + i * 32 + er;   // 0..63
        uint4 v;
        v.x = W[e][pc + 0];
        v.y = W[e][pc + 1];
        v.z = W[e][pc + 2];
        v.w = W[e][pc + 3];
        unsigned int* dst =
            reinterpret_cast<unsigned int*>(xTb + (size_t)(e0 + e) * T_LEN + t0);
        *reinterpret_cast<uint4*>(dst + pc) = v;
    }
}

// ---------------------------------------------------------------------------
// Prepass 2: 8 shift-staggered bf16 copies of the reversed, zero-padded weight.
//   wrev[j] = (j < T) ? w[T-1-j] : 0 ;  wrevs[p][q] = wrev[q + p]
// ---------------------------------------------------------------------------
__global__ __launch_bounds__(256) void build_wrevs(
    const float* __restrict__ w, __hip_bfloat16* __restrict__ wrevs)
{
    int total = 8 * WREV_LEN;
    for (int i = threadIdx.x + blockIdx.x * blockDim.x; i < total;
         i += blockDim.x * gridDim.x) {
        int p = i / WREV_LEN, q = i - p * WREV_LEN;
        int j = q + p;
        float v = (j < T_LEN) ? w[T_LEN - 1 - j] : 0.0f;
        wrevs[i] = __float2bfloat16(v);
    }
}

// ---------------------------------------------------------------------------
// 8-phase-style 256x256 GEMM: D[e,s] = sum_t xT[b][e][t] * w[s-t]
// A: [256e][64t] bf16, TRIPLE-buffered, global_load_lds staged with both-sides
//    XOR chunk swizzle (linear LDS dest, src chunk p^(r&7), read chunk q^(r&7)).
//    Prefetch depth 2 tiles -> per-tile boundary wait is vmcnt(4), never 0.
// B: wrev window (8 shifted copies x CL bf16) filled ONCE into LDS; copy
//    stride 1156 words (== 4 mod 8) makes the 8 copies tile all 32 banks ->
//    conflict-free broadcast b128 reads. No VMEM in K-loop except stage.
// Phases per K-tile (Gray order over C-quadrants mh,nh):
//   (0,0)ldA+ldB (1,0)ldA (1,1)ldB (0,1)ldA ; each phase:
//   ds_reads -> 1 stage call -> barrier -> lgkmcnt(0) -> sched_barrier ->
//   setprio(1) -> 16 MFMA -> setprio(0) -> barrier. vmcnt(4) once per tile.
// grid 512 = 8 XCD chunks x 64; panel-major within chunk, heavy-first.
// block 512 (8 waves = 2M x 4N, 128x64 out per wave, acc[8][4]).
// ---------------------------------------------------------------------------
#define LOAD_A(MH)                                                             \
    _Pragma("unroll")                                                          \
    for (int m4 = 0; m4 < 4; ++m4) {                                           \
        const int r = arow + ((MH) * 4 + m4) * 16;                             \
        afr[m4][0] = *reinterpret_cast<const short8*>(Ab + r * 128 + xq0 * 16);\
        afr[m4][1] = *reinterpret_cast<const short8*>(Ab + r * 128 + xq1 * 16);\
    }

#define LOAD_B(NH)                                                             \
    _Pragma("unroll")                                                          \
    for (int n2 = 0; n2 < 2; ++n2) {                                           \
        _Pragma("unroll")                                                      \
        for (int kk = 0; kk < 2; ++kk) {                                       \
            const int C = Cb + t0 + kk * 32 - ((NH) * 2 + n2) * 16;            \
            const int p = C & 7;                                               \
            bfr[n2][kk] = *reinterpret_cast<const short8*>(                    \
                L + BOFF + p * (CL * 2) + ((C - p) - Wbase) * 2);              \
        }                                                                      \
    }

#define MFMA16(MH, NH)                                                         \
    _Pragma("unroll")                                                          \
    for (int kk = 0; kk < 2; ++kk)                                             \
        _Pragma("unroll")                                                      \
        for (int m4 = 0; m4 < 4; ++m4)                                         \
            _Pragma("unroll")                                                  \
            for (int n2 = 0; n2 < 2; ++n2)                                     \
                acc[(MH) * 4 + m4][(NH) * 2 + n2] =                            \
                    __builtin_amdgcn_mfma_f32_16x16x32_bf16(                   \
                        afr[m4][kk], bfr[n2][kk],                              \
                        acc[(MH) * 4 + m4][(NH) * 2 + n2], 0, 0, 0);

#define PHASE_SYNC_PRE()                                                       \
    __builtin_amdgcn_s_barrier();                                              \
    asm volatile("s_waitcnt lgkmcnt(0)" ::: "memory");                         \
    __builtin_amdgcn_sched_barrier(0);                                         \
    __builtin_amdgcn_s_setprio(1);

#define PHASE_SYNC_POST()                                                      \
    __builtin_amdgcn_s_setprio(0);                                             \
    __builtin_amdgcn_s_barrier();

__global__ __launch_bounds__(512, 2) void toeplitz_gemm(
    const __hip_bfloat16* __restrict__ xT,
    const __hip_bfloat16* __restrict__ wrevs,
    const float* __restrict__ bias,
    float* __restrict__ out)
{
    __shared__ __align__(16) char L[3 * ABUF_B + 8 * CL * 2];   // 135296 B

    const int bid = blockIdx.x;
    const int lid = (bid & 7) * 64 + (bid >> 3);      // XCD chunk, bijective
    const int nb = 7 - (lid & 7);                     // heavy-first in panel
    const int panel = lid >> 3;                       // 0..63
    const int mb = panel & 7, b = panel >> 3;
    const int e0 = mb * BM, s0 = nb * BN;
    const int tid = threadIdx.x;
    const int wave = tid >> 6, lane = tid & 63;
    const int wm = (wave >> 2) * 128;                 // wave e offset (2 rows)
    const int wn = (wave & 3) * 64;                   // wave s offset (4 cols)
    const int ln15 = lane & 15, quad = lane >> 4, ln7 = lane & 7;

    const int ktiles = (s0 + BN) / BK2;               // 4*(nb+1): 4..32
    const int Wbase = T_LEN - 264 - s0;               // Cmin-8 (8-aligned, can be <0)
    const __hip_bfloat16* xTb = xT + ((size_t)b * E_LEN + e0) * T_LEN;

    // ---- one-time B window fill: L_B[p][i] = wrevs[p][Wbase+i]  (i<CL)
    for (int i = tid; i < 8 * (CL / 8); i += 512) {   // CL/8 = 289 uint4/copy
        const int p = i / (CL / 8), c = i - p * (CL / 8);
        int q = Wbase + c * 8;                        // bf16 index into copy p
        if (q < 0) q = 0;                             // pad region, never read
        const uint4 v = *(reinterpret_cast<const uint4*>(
            wrevs + (size_t)p * WREV_LEN + q));
        *(reinterpret_cast<uint4*>(L + BOFF + (size_t)p * (CL * 2)) + c) = v;
    }
    __syncthreads();

    floatx4 acc[8][4];
    #pragma unroll
    for (int i = 0; i < 8; ++i)
        #pragma unroll
        for (int j = 0; j < 4; ++j)
            acc[i][j] = (floatx4){0.f, 0.f, 0.f, 0.f};

    // stage one 8KB quarter (call cc) of tile kt2 into buffer buf
    auto STAGE1 = [&](int buf, int kt2, int cc) {
        const int t0n = kt2 * BK2;
        const int c = cc * 512 + tid;                 // 16B chunk id 0..2047
        const int r = c >> 3, p = c & 7;
        const int ps = p ^ (r & 7);                   // inverse-swizzled source
        const __hip_bfloat16* g = xTb + (size_t)r * T_LEN + t0n + ps * 8;
        __builtin_amdgcn_global_load_lds(
            (gas_ptr)g,
            (lds_ptr)(L + buf * ABUF_B + (cc * 512 + wave * 64) * 16), 16, 0, 0);
    };

    // prologue: stage tiles 0 and 1 (ktiles >= 4 always)
    STAGE1(0, 0, 0); STAGE1(0, 0, 1); STAGE1(0, 0, 2); STAGE1(0, 0, 3);
    STAGE1(1, 1, 0); STAGE1(1, 1, 1); STAGE1(1, 1, 2); STAGE1(1, 1, 3);
    asm volatile("s_waitcnt vmcnt(4)" ::: "memory");  // tile 0 resident
    __builtin_amdgcn_s_barrier();

    const int arow = wm + ln15;
    const int xq0 = quad ^ ln7;                       // swizzled chunk, kk=0
    const int xq1 = (4 + quad) ^ ln7;                 // swizzled chunk, kk=1
    const int Cb = (T_LEN - 1 - s0 - wn - ln15) + quad * 8;

    short8 afr[4][2], bfr[2][2];
    int bi = 0;
    for (int kt = 0; kt < ktiles; ++kt) {
        const int t0 = kt * BK2;
        const char* Ab = L + bi * ABUF_B;
        const int pf = (kt + 2 < ktiles);
        const int bp = (bi + 2 >= 3) ? bi - 1 : bi + 2;   // (kt+2)%3

        // phase 0: quadrant (0,0)
        LOAD_A(0) LOAD_B(0)
        if (pf) STAGE1(bp, kt + 2, 0);
        PHASE_SYNC_PRE()
        MFMA16(0, 0)
        PHASE_SYNC_POST()

        // phase 1: quadrant (1,0) — reuse B
        LOAD_A(1)
        if (pf) STAGE1(bp, kt + 2, 1);
        PHASE_SYNC_PRE()
        MFMA16(1, 0)
        PHASE_SYNC_POST()

        // phase 2: quadrant (1,1) — reuse A
        LOAD_B(1)
        if (pf) STAGE1(bp, kt + 2, 2);
        PHASE_SYNC_PRE()
        MFMA16(1, 1)
        PHASE_SYNC_POST()

        // phase 3: quadrant (0,1) — reload A(0), reuse B
        LOAD_A(0)
        if (pf) STAGE1(bp, kt + 2, 3);
        PHASE_SYNC_PRE()
        MFMA16(0, 1)
        __builtin_amdgcn_s_setprio(0);
        // boundary: tile kt+1 must be resident; keep kt+2's 4 calls in flight
        if (pf) asm volatile("s_waitcnt vmcnt(4)" ::: "memory");
        else    asm volatile("s_waitcnt vmcnt(0)" ::: "memory");
        __builtin_amdgcn_s_barrier();

        bi = (bi + 1 == 3) ? 0 : bi + 1;
    }

    // epilogue: out[b][s][e] = acc + bias[s]
    // C/D layout: col(=s) = lane&15, row(=e) = quad*4 + reg
    #pragma unroll
    for (int ni = 0; ni < 4; ++ni) {
        const int s = s0 + wn + ni * 16 + ln15;
        const float bv = bias[s];
        #pragma unroll
        for (int mi = 0; mi < 8; ++mi) {
            const int e = e0 + wm + mi * 16 + quad * 4;
            float* dst = out + ((size_t)b * T_LEN + s) * E_LEN + e;
            floatx4 v = acc[mi][ni];
            v.x += bv; v.y += bv; v.z += bv; v.w += bv;
            *reinterpret_cast<floatx4*>(dst) = v;
        }
    }
}

// ---------------------------------------------------------------------------
extern "C" void kernel_launch(void* const* d_in, const int* in_sizes, int n_in,
                              void* d_out, int out_size, void* d_ws, size_t ws_size,
                              hipStream_t stream)
{
    const float* x    = (const float*)d_in[0];
    const float* w    = (const float*)d_in[1];
    const float* bias = (const float*)d_in[2];
    float* out = (float*)d_out;

    // workspace: [xT bf16: B*E*T] [wrevs bf16: 8*WREV_LEN]
    __hip_bfloat16* xT = (__hip_bfloat16*)d_ws;
    __hip_bfloat16* wrevs =
        (__hip_bfloat16*)((char*)d_ws + (size_t)B_SZ * E_LEN * T_LEN * 2);

    transpose_cast<<<dim3(T_LEN / 64, E_LEN / 64, B_SZ), 256, 0, stream>>>(x, xT);
    build_wrevs<<<dim3(64), 256, 0, stream>>>(w, wrevs);
    toeplitz_gemm<<<dim3(512), 512, 0, stream>>>(xT, wrevs, bias, out);
}

// Round 4
// 298.945 us; speedup vs baseline: 1.6249x; 1.1589x over previous
//
#include <hip/hip_runtime.h>
#include <hip/hip_bf16.h>

#define T_LEN 2048
#define E_LEN 2048
#define B_SZ  8
#define BM 256
#define BN 256
#define BK2 64          // k-tile (two 32-k MFMA half-steps per tile)
#define WREV_LEN 4104   // 2*T + 8, even -> each shifted copy stays 16B aligned
#define CL 2312         // per-copy bf16 length of LDS B window (1156 words % 8 == 4)
#define ABUF_B 32768    // bytes per A buffer (256*64*2)
#define BOFF (3 * ABUF_B)

typedef short short8 __attribute__((ext_vector_type(8)));
typedef float floatx4 __attribute__((ext_vector_type(4)));

typedef const __attribute__((address_space(1))) void* gas_ptr;
typedef __attribute__((address_space(3))) void* lds_ptr;

// ---------------------------------------------------------------------------
// Prepass 1: xT[b][e][t] = bf16(x[b][t][e])   (~BW-floor, proven R1)
// ---------------------------------------------------------------------------
__global__ __launch_bounds__(256) void transpose_cast(
    const float* __restrict__ x, __hip_bfloat16* __restrict__ xT)
{
    const int t0 = blockIdx.x * 64, e0 = blockIdx.y * 64, b = blockIdx.z;
    __shared__ unsigned int W[64][33];       // [e][t-pair], 8448 B
    const int tid = threadIdx.x;
    const int wave = tid >> 6, lane = tid & 63;

    const float* xb = x + (size_t)b * T_LEN * E_LEN;
    const int c = tid & 15;                  // e-quad index (e = 4c..4c+3)
    const int q = tid >> 4;                  // t-pair base (0..15)

    #pragma unroll
    for (int i = 0; i < 2; ++i) {
        const int tp = q + 16 * i;           // t-pair 0..31
        const float4 a4 = *reinterpret_cast<const float4*>(
            xb + (size_t)(t0 + 2 * tp) * E_LEN + e0 + 4 * c);
        const float4 b4 = *reinterpret_cast<const float4*>(
            xb + (size_t)(t0 + 2 * tp + 1) * E_LEN + e0 + 4 * c);
        const float av[4] = {a4.x, a4.y, a4.z, a4.w};
        const float bv[4] = {b4.x, b4.y, b4.z, b4.w};
        #pragma unroll
        for (int j = 0; j < 4; ++j) {
            __hip_bfloat16 ha = __float2bfloat16(av[j]);
            __hip_bfloat16 hb = __float2bfloat16(bv[j]);
            unsigned int w =
                (unsigned int)*reinterpret_cast<unsigned short*>(&ha) |
                ((unsigned int)*reinterpret_cast<unsigned short*>(&hb) << 16);
            W[4 * c + j][tp] = w;
        }
    }
    __syncthreads();

    __hip_bfloat16* xTb = xT + (size_t)b * E_LEN * T_LEN;
    const int er = lane >> 3;                // 0..7
    const int pc = (lane & 7) * 4;           // uint col 0,4,..,28
    #pragma unroll
    for (int i = 0; i < 2; ++i) {
        const int e = wave * 8 + i * 32 + er;   // 0..63
        uint4 v;
        v.x = W[e][pc + 0];
        v.y = W[e][pc + 1];
        v.z = W[e][pc + 2];
        v.w = W[e][pc + 3];
        unsigned int* dst =
            reinterpret_cast<unsigned int*>(xTb + (size_t)(e0 + e) * T_LEN + t0);
        *reinterpret_cast<uint4*>(dst + pc) = v;
    }
}

// ---------------------------------------------------------------------------
// Prepass 2: 8 shift-staggered bf16 copies of the reversed, zero-padded weight.
// ---------------------------------------------------------------------------
__global__ __launch_bounds__(256) void build_wrevs(
    const float* __restrict__ w, __hip_bfloat16* __restrict__ wrevs)
{
    int total = 8 * WREV_LEN;
    for (int i = threadIdx.x + blockIdx.x * blockDim.x; i < total;
         i += blockDim.x * gridDim.x) {
        int p = i / WREV_LEN, q = i - p * WREV_LEN;
        int j = q + p;
        float v = (j < T_LEN) ? w[T_LEN - 1 - j] : 0.0f;
        wrevs[i] = __float2bfloat16(v);
    }
}

// ---------------------------------------------------------------------------
// 256x256 GEMM, uniform-work pair blocks: D[e,s] = sum_t xT[b][e][t] * w[s-t]
// grid 256 (1 block/CU), block 512 (8 waves = 2M x 4N, 128x64 out/wave).
// Each block runs TWO output tiles on the SAME panel: nb=7-pi then nb=pi
// -> exactly 36 k-tiles per block (zero imbalance), A-panel L2-hot for run 2.
// A: [256e][64t] bf16, triple-buffered global_load_lds, both-sides XOR chunk
//    swizzle; prefetch depth 2, boundary wait vmcnt(4) (never 0 mid-loop).
// B: wrev window in LDS (8 shifted copies, stride 1156 words == 4 mod 8 ->
//    copies tile all 32 banks), filled once per run.
// Schedule per k-tile (ONE barrier, free-running waves):
//   STAGE(kt+2) x4 ; ds_read afr0,bfr0,afr1 ; MFMA32(kk0) [hides afr1 drain];
//   ds_read bfr1 ; MFMA32(kk1) ; vmcnt(4) ; s_barrier.
// Within a tile reads hit buf bi while DMA writes buf bi+2 -> no LDS hazard,
// so no intra-tile barriers; compiler emits fine-grained lgkmcnt waits.
// XCD grouping: xcd = bid&7; panels xcd*8..xcd*8+7 live on one XCD.
// ---------------------------------------------------------------------------
#define LOAD_A8(dst, KK)                                                       \
    _Pragma("unroll")                                                          \
    for (int mi = 0; mi < 8; ++mi) {                                           \
        const int r = wm + mi * 16 + ln15;                                     \
        const int xq = ((KK) * 4 + quad) ^ (ln15 & 7);                         \
        dst[mi] = *reinterpret_cast<const short8*>(Ab + r * 128 + xq * 16);    \
    }

#define LOAD_B4(dst, KK)                                                       \
    _Pragma("unroll")                                                          \
    for (int ni = 0; ni < 4; ++ni) {                                           \
        const int C = Cb + t0 + (KK) * 32 - ni * 16;                           \
        const int p = C & 7;                                                   \
        dst[ni] = *reinterpret_cast<const short8*>(                            \
            L + BOFF + p * (CL * 2) + ((C - p) - Wbase) * 2);                  \
    }

#define MFMA32(Af, Bf)                                                         \
    _Pragma("unroll")                                                          \
    for (int ni = 0; ni < 4; ++ni)                                             \
        _Pragma("unroll")                                                      \
        for (int mi = 0; mi < 8; ++mi)                                         \
            acc[mi][ni] = __builtin_amdgcn_mfma_f32_16x16x32_bf16(             \
                Af[mi], Bf[ni], acc[mi][ni], 0, 0, 0);

__global__ __launch_bounds__(512, 2) void toeplitz_gemm(
    const __hip_bfloat16* __restrict__ xT,
    const __hip_bfloat16* __restrict__ wrevs,
    const float* __restrict__ bias,
    float* __restrict__ out)
{
    __shared__ __align__(16) char L[3 * ABUF_B + 8 * CL * 2];   // 135296 B

    const int bid = blockIdx.x;
    const int xcd = bid & 7, r5 = bid >> 3;           // r5: 0..31
    const int panel = xcd * 8 + (r5 & 7);             // 0..63, grouped per XCD
    const int pi = r5 >> 3;                           // 0..3 pair index
    const int mb = panel & 7, b = panel >> 3;
    const int e0 = mb * BM;
    const int tid = threadIdx.x;
    const int wave = tid >> 6, lane = tid & 63;
    const int wm = (wave >> 2) * 128;                 // wave e offset
    const int wn = (wave & 3) * 64;                   // wave s offset
    const int ln15 = lane & 15, quad = lane >> 4;

    const __hip_bfloat16* xTb = xT + ((size_t)b * E_LEN + e0) * T_LEN;

    // stage one 8KB quarter (call cc) of tile kt2 into buffer buf
    auto STAGE1 = [&](int buf, int kt2, int cc) {
        const int t0n = kt2 * BK2;
        const int c = cc * 512 + tid;                 // 16B chunk id 0..2047
        const int rr = c >> 3, p = c & 7;
        const int ps = p ^ (rr & 7);                  // inverse-swizzled source
        const __hip_bfloat16* g = xTb + (size_t)rr * T_LEN + t0n + ps * 8;
        __builtin_amdgcn_global_load_lds(
            (gas_ptr)g,
            (lds_ptr)(L + buf * ABUF_B + (cc * 512 + wave * 64) * 16), 16, 0, 0);
    };

    for (int run = 0; run < 2; ++run) {
        const int nb = (run == 0) ? 7 - pi : pi;      // heavy run first
        const int s0 = nb * BN;
        const int ktiles = 4 * (nb + 1);              // 4..32
        const int Wbase = T_LEN - 264 - s0;           // 8-aligned, may be <0
        const int Cb = (T_LEN - 1 - s0 - wn - ln15) + quad * 8;

        // ---- B window fill: L_B[p][i] = wrevs[p][Wbase+i]  (i<CL)
        __syncthreads();                              // safe overwrite (run 1)
        for (int i = tid; i < 8 * (CL / 8); i += 512) {
            const int p = i / (CL / 8), c = i - p * (CL / 8);
            int q = Wbase + c * 8;
            if (q < 0) q = 0;                         // pad region, never read
            const uint4 v = *(reinterpret_cast<const uint4*>(
                wrevs + (size_t)p * WREV_LEN + q));
            *(reinterpret_cast<uint4*>(L + BOFF + (size_t)p * (CL * 2)) + c) = v;
        }

        floatx4 acc[8][4];
        #pragma unroll
        for (int i = 0; i < 8; ++i)
            #pragma unroll
            for (int j = 0; j < 4; ++j)
                acc[i][j] = (floatx4){0.f, 0.f, 0.f, 0.f};

        // prologue: stage tiles 0 and 1 (ktiles >= 4 always)
        STAGE1(0, 0, 0); STAGE1(0, 0, 1); STAGE1(0, 0, 2); STAGE1(0, 0, 3);
        STAGE1(1, 1, 0); STAGE1(1, 1, 1); STAGE1(1, 1, 2); STAGE1(1, 1, 3);
        // drain own ds_writes (B fill) + tile-0 DMAs, then rendezvous
        asm volatile("s_waitcnt vmcnt(4) lgkmcnt(0)" ::: "memory");
        __builtin_amdgcn_s_barrier();

        int bi = 0;
        for (int kt = 0; kt < ktiles; ++kt) {
            const int t0 = kt * BK2;
            const char* Ab = L + bi * ABUF_B;
            const bool pf = (kt + 2 < ktiles);
            const int bp = (bi + 2 >= 3) ? bi - 1 : bi + 2;   // (kt+2)%3

            if (pf) {
                STAGE1(bp, kt + 2, 0); STAGE1(bp, kt + 2, 1);
                STAGE1(bp, kt + 2, 2); STAGE1(bp, kt + 2, 3);
            }

            short8 afr0[8], bfr0[4], afr1[8], bfr1[4];
            LOAD_A8(afr0, 0)
            LOAD_B4(bfr0, 0)
            LOAD_A8(afr1, 1)                  // drains under MFMA(kk0)

            __builtin_amdgcn_s_setprio(1);
            MFMA32(afr0, bfr0)
            __builtin_amdgcn_s_setprio(0);

            LOAD_B4(bfr1, 1)

            __builtin_amdgcn_s_setprio(1);
            MFMA32(afr1, bfr1)
            __builtin_amdgcn_s_setprio(0);

            // boundary: tile kt+1 must be resident; keep kt+2's 4 in flight
            if (pf) asm volatile("s_waitcnt vmcnt(4)" ::: "memory");
            else    asm volatile("s_waitcnt vmcnt(0)" ::: "memory");
            __builtin_amdgcn_s_barrier();

            bi = (bi + 1 == 3) ? 0 : bi + 1;
        }

        // epilogue: out[b][s][e] = acc + bias[s]
        // C/D layout: col(=s) = lane&15, row(=e) = quad*4 + reg
        #pragma unroll
        for (int ni = 0; ni < 4; ++ni) {
            const int s = s0 + wn + ni * 16 + ln15;
            const float bv = bias[s];
            #pragma unroll
            for (int mi = 0; mi < 8; ++mi) {
                const int e = e0 + wm + mi * 16 + quad * 4;
                float* dst = out + ((size_t)b * T_LEN + s) * E_LEN + e;
                floatx4 v = acc[mi][ni];
                v.x += bv; v.y += bv; v.z += bv; v.w += bv;
                *reinterpret_cast<floatx4*>(dst) = v;
            }
        }
    }
}

// ---------------------------------------------------------------------------
extern "C" void kernel_launch(void* const* d_in, const int* in_sizes, int n_in,
                              void* d_out, int out_size, void* d_ws, size_t ws_size,
                              hipStream_t stream)
{
    const float* x    = (const float*)d_in[0];
    const float* w    = (const float*)d_in[1];
    const float* bias = (const float*)d_in[2];
    float* out = (float*)d_out;

    // workspace: [xT bf16: B*E*T] [wrevs bf16: 8*WREV_LEN]
    __hip_bfloat16* xT = (__hip_bfloat16*)d_ws;
    __hip_bfloat16* wrevs =
        (__hip_bfloat16*)((char*)d_ws + (size_t)B_SZ * E_LEN * T_LEN * 2);

    transpose_cast<<<dim3(T_LEN / 64, E_LEN / 64, B_SZ), 256, 0, stream>>>(x, xT);
    build_wrevs<<<dim3(64), 256, 0, stream>>>(w, wrevs);
    toeplitz_gemm<<<dim3(256), 512, 0, stream>>>(xT, wrevs, bias, out);
}

// Round 5
// 298.366 us; speedup vs baseline: 1.6280x; 1.0019x over previous
//
#include <hip/hip_runtime.h>
#include <hip/hip_bf16.h>

#define T_LEN 2048
#define E_LEN 2048
#define B_SZ  8
#define BM 256
#define BN 256
#define BK2 64          // k-tile (two 32-k MFMA half-steps per tile)
#define WREV_LEN 4104   // 2*T + 8, even -> each shifted copy stays 16B aligned
#define CL 2312         // per-copy bf16 length of LDS B window (1156 words % 8 == 4)
#define ABUF_B 32768    // bytes per A buffer (256*64*2)
#define BOFF (2 * ABUF_B)

typedef short short8 __attribute__((ext_vector_type(8)));
typedef float floatx4 __attribute__((ext_vector_type(4)));

// ---------------------------------------------------------------------------
// Prepass: 8 shift-staggered bf16 copies of the reversed, zero-padded weight.
//   wrev[j] = (j < T) ? w[T-1-j] : 0 ;  wrevs[p][q] = wrev[q + p]
// ---------------------------------------------------------------------------
__global__ __launch_bounds__(256) void build_wrevs(
    const float* __restrict__ w, __hip_bfloat16* __restrict__ wrevs)
{
    int total = 8 * WREV_LEN;
    for (int i = threadIdx.x + blockIdx.x * blockDim.x; i < total;
         i += blockDim.x * gridDim.x) {
        int p = i / WREV_LEN, q = i - p * WREV_LEN;
        int j = q + p;
        float v = (j < T_LEN) ? w[T_LEN - 1 - j] : 0.0f;
        wrevs[i] = __float2bfloat16(v);
    }
}

// ---------------------------------------------------------------------------
// FUSED transpose+GEMM: D[e,s] = sum_t x[b][t][e] * w[s-t]  (== out[b][s][e])
// No xT prepass. Staging map: lane -> 4 consecutive e, wave -> t-octet.
// Thread's 8 coalesced float4 loads (8 t-rows x its 4 e) already hold full
// 8-t chunks per e-row -> transpose is free in registers; pack bf16 pairs,
// 4x ds_write_b128 into A-tile [r=e 0..255][8 chunk slots].
// Chunk slot s(r,q) = q ^ (r&7) ^ ((r>>3)&7):
//   writes (r = 4*lane+j): slots uniform over 8 -> conflict-free
//   frag reads (r = 16-aligned + ln15): 8 distinct slots per 8 rows -> 2-way
// B: wrev window in LDS (8 shifted copies, stride 1156 words == 4 mod 8 ->
//    copies tile all 32 banks), filled once per run.
// K-loop (ONE raw barrier/tile, lgkmcnt(0) only -> x loads stay in flight):
//   PACK+write(buf^1) ; issue loads(kt+2) ; frags+MFMA(buf) ; lgkm0+s_barrier
// grid 256 (1 block/CU), block 512 (8 waves = 2M x 4N, 128x64 out/wave).
// Block runs TWO tiles of same panel (nb = 7-pi, pi) -> 36 k-tiles/block,
// zero imbalance; XCD grouping keeps a panel's 4 blocks on one XCD (L2-hot x).
// ---------------------------------------------------------------------------
#define LOAD_A8(dst, KK)                                                       \
    _Pragma("unroll")                                                          \
    for (int mi = 0; mi < 8; ++mi) {                                           \
        const int r = wm + mi * 16 + ln15;                                     \
        const int xq = ((KK) * 4 + quad) ^ (r & 7) ^ ((r >> 3) & 7);           \
        dst[mi] = *reinterpret_cast<const short8*>(Ab + r * 128 + xq * 16);    \
    }

#define LOAD_B4(dst, KK)                                                       \
    _Pragma("unroll")                                                          \
    for (int ni = 0; ni < 4; ++ni) {                                           \
        const int C = Cb + t0 + (KK) * 32 - ni * 16;                           \
        const int p = C & 7;                                                   \
        dst[ni] = *reinterpret_cast<const short8*>(                            \
            Lsh + BOFF + p * (CL * 2) + ((C - p) - Wbase) * 2);                \
    }

#define MFMA32(Af, Bf)                                                         \
    _Pragma("unroll")                                                          \
    for (int ni = 0; ni < 4; ++ni)                                             \
        _Pragma("unroll")                                                      \
        for (int mi = 0; mi < 8; ++mi)                                         \
            acc[mi][ni] = __builtin_amdgcn_mfma_f32_16x16x32_bf16(             \
                Af[mi], Bf[ni], acc[mi][ni], 0, 0, 0);

#define TILE_BARRIER()                                                         \
    asm volatile("s_waitcnt lgkmcnt(0)\n\ts_barrier" ::: "memory");

__global__ __launch_bounds__(512, 2) void toeplitz_gemm(
    const float* __restrict__ x,
    const __hip_bfloat16* __restrict__ wrevs,
    const float* __restrict__ bias,
    float* __restrict__ out)
{
    __shared__ __align__(16) char Lsh[BOFF + 8 * CL * 2];   // 102528 B

    const int bid = blockIdx.x;
    const int xcd = bid & 7, r5 = bid >> 3;           // r5: 0..31
    const int panel = xcd * 8 + (r5 & 7);             // 0..63, grouped per XCD
    const int pi = r5 >> 3;                           // 0..3 pair index
    const int mb = panel & 7, b = panel >> 3;
    const int e0 = mb * BM;
    const int tid = threadIdx.x;
    const int wave = tid >> 6, lane = tid & 63;
    const int wm = (wave >> 2) * 128;                 // wave e offset
    const int wn = (wave & 3) * 64;                   // wave s offset
    const int ln15 = lane & 15, quad = lane >> 4;

    const float* xb = x + (size_t)b * T_LEN * E_LEN + e0;

    float4 La[8];                                     // x rows t = 8*wave+tt
    auto LOADX = [&](int kt2) {
        const float* g = xb + (size_t)(kt2 * BK2 + 8 * wave) * E_LEN + 4 * lane;
        #pragma unroll
        for (int tt = 0; tt < 8; ++tt)
            La[tt] = *reinterpret_cast<const float4*>(g + (size_t)tt * E_LEN);
    };
    // pack La -> 4 chunks (r = 4*lane+j, q = wave), conflict-free b128 writes
    auto PACKWRITE = [&](int buf) {
        char* base = Lsh + buf * ABUF_B;
        #pragma unroll
        for (int j = 0; j < 4; ++j) {
            const int r = 4 * lane + j;
            const int s = wave ^ (r & 7) ^ ((r >> 3) & 7);
            unsigned int tmp[4];
            #pragma unroll
            for (int k = 0; k < 4; ++k) {
                const float fa[4] = {La[2 * k].x, La[2 * k].y,
                                     La[2 * k].z, La[2 * k].w};
                const float fb[4] = {La[2 * k + 1].x, La[2 * k + 1].y,
                                     La[2 * k + 1].z, La[2 * k + 1].w};
                __hip_bfloat16 ha = __float2bfloat16(fa[j]);
                __hip_bfloat16 hb = __float2bfloat16(fb[j]);
                tmp[k] =
                    (unsigned int)*reinterpret_cast<unsigned short*>(&ha) |
                    ((unsigned int)*reinterpret_cast<unsigned short*>(&hb) << 16);
            }
            uint4 wv = {tmp[0], tmp[1], tmp[2], tmp[3]};
            *reinterpret_cast<uint4*>(base + r * 128 + s * 16) = wv;
        }
    };

    for (int run = 0; run < 2; ++run) {
        const int nb = (run == 0) ? 7 - pi : pi;      // heavy run first
        const int s0 = nb * BN;
        const int ktiles = 4 * (nb + 1);              // 4..32
        const int Wbase = T_LEN - 264 - s0;           // 8-aligned, may be <0
        const int Cb = (T_LEN - 1 - s0 - wn - ln15) + quad * 8;

        __syncthreads();                              // safe overwrite (run 1)
        // ---- B window fill: L_B[p][i] = wrevs[p][Wbase+i]  (i<CL)
        for (int i = tid; i < 8 * (CL / 8); i += 512) {
            const int p = i / (CL / 8), c = i - p * (CL / 8);
            int q = Wbase + c * 8;
            if (q < 0) q = 0;                         // pad region, never read
            const uint4 v = *(reinterpret_cast<const uint4*>(
                wrevs + (size_t)p * WREV_LEN + q));
            *(reinterpret_cast<uint4*>(Lsh + BOFF + (size_t)p * (CL * 2)) + c) = v;
        }

        floatx4 acc[8][4];
        #pragma unroll
        for (int i = 0; i < 8; ++i)
            #pragma unroll
            for (int j = 0; j < 4; ++j)
                acc[i][j] = (floatx4){0.f, 0.f, 0.f, 0.f};

        // prologue: tile 0 staged to buf0; tile 1 loads in flight
        LOADX(0);
        PACKWRITE(0);
        LOADX(1);
        TILE_BARRIER();

        int cur = 0;
        for (int kt = 0; kt < ktiles; ++kt) {
            const int t0 = kt * BK2;
            const char* Ab = Lsh + cur * ABUF_B;

            if (kt + 1 < ktiles) PACKWRITE(cur ^ 1);  // La(kt+1) -> other buf
            if (kt + 2 < ktiles) LOADX(kt + 2);       // issue next loads

            short8 afr[8], bfr[4];
            LOAD_A8(afr, 0)
            LOAD_B4(bfr, 0)
            __builtin_amdgcn_s_setprio(1);
            MFMA32(afr, bfr)
            __builtin_amdgcn_s_setprio(0);

            LOAD_A8(afr, 1)
            LOAD_B4(bfr, 1)
            __builtin_amdgcn_s_setprio(1);
            MFMA32(afr, bfr)
            __builtin_amdgcn_s_setprio(0);

            // drain ds writes/reads only; x loads stay in flight
            TILE_BARRIER();
            cur ^= 1;
        }

        // epilogue: out[b][s][e] = acc + bias[s]
        // C/D layout: col(=s) = lane&15, row(=e) = quad*4 + reg
        #pragma unroll
        for (int ni = 0; ni < 4; ++ni) {
            const int s = s0 + wn + ni * 16 + ln15;
            const float bv = bias[s];
            #pragma unroll
            for (int mi = 0; mi < 8; ++mi) {
                const int e = e0 + wm + mi * 16 + quad * 4;
                float* dst = out + ((size_t)b * T_LEN + s) * E_LEN + e;
                floatx4 v = acc[mi][ni];
                v.x += bv; v.y += bv; v.z += bv; v.w += bv;
                *reinterpret_cast<floatx4*>(dst) = v;
            }
        }
    }
}

// ---------------------------------------------------------------------------
extern "C" void kernel_launch(void* const* d_in, const int* in_sizes, int n_in,
                              void* d_out, int out_size, void* d_ws, size_t ws_size,
                              hipStream_t stream)
{
    const float* x    = (const float*)d_in[0];
    const float* w    = (const float*)d_in[1];
    const float* bias = (const float*)d_in[2];
    float* out = (float*)d_out;

    // workspace: [wrevs bf16: 8*WREV_LEN]
    __hip_bfloat16* wrevs = (__hip_bfloat16*)d_ws;

    build_wrevs<<<dim3(64), 256, 0, stream>>>(w, wrevs);
    toeplitz_gemm<<<dim3(256), 512, 0, stream>>>(x, wrevs, bias, out);
}